// Round 1
// baseline (256.066 us; speedup 1.0000x reference)
//
#include <hip/hip_runtime.h>

// TNorm: out[b] = outer(g0, g1, g2, g3) flattened, g = x[b].reshape(4, 8).
// B=16384 rows, 32 inputs/row, 4096 outputs/row (fp32).
// Write-stream bound: 256 MiB out + 2 MiB in -> ~43 us floor at 6.3 TB/s.

#define NUM_MF 8
#define ROW_IN 32
#define ROW_OUT 4096

__global__ __launch_bounds__(256) void TNorm_71038759076547_kernel(
    const float* __restrict__ x, float* __restrict__ out) {
    __shared__ float g[ROW_IN];

    const int row = blockIdx.x;
    const int t = threadIdx.x;

    // Stage the 32-float row into LDS with 8 float4 loads.
    if (t < 8) {
        ((float4*)g)[t] = ((const float4*)(x + (size_t)row * ROW_IN))[t];
    }
    __syncthreads();

    const float* g0 = g;
    const float* g1 = g + 8;
    const float* g2 = g + 16;
    const float* g3 = g + 24;

    // Two halves of g3, reused across all 4 stores.
    const float4 g3lo = make_float4(g3[0], g3[1], g3[2], g3[3]);
    const float4 g3hi = make_float4(g3[4], g3[5], g3[6], g3[7]);

    float4* out4 = (float4*)(out + (size_t)row * ROW_OUT);

    // 1024 float4s per row; 256 threads x 4 iterations, coalesced:
    // consecutive lanes write consecutive 16B chunks.
#pragma unroll
    for (int i = 0; i < 4; ++i) {
        const int v = t + 256 * i;   // float4 index in row, 0..1023
        const int e = v << 2;        // element index; m = e&7, l=(e>>3)&7, k=(e>>6)&7, j=(e>>9)&7
        const int j = (e >> 9) & 7;
        const int k = (e >> 6) & 7;
        const int l = (e >> 3) & 7;
        const float s = g0[j] * g1[k] * g2[l];
        const float4 gm = (e & 4) ? g3hi : g3lo;
        float4 r;
        r.x = s * gm.x;
        r.y = s * gm.y;
        r.z = s * gm.z;
        r.w = s * gm.w;
        out4[v] = r;
    }
}

extern "C" void kernel_launch(void* const* d_in, const int* in_sizes, int n_in,
                              void* d_out, int out_size, void* d_ws, size_t ws_size,
                              hipStream_t stream) {
    const float* x = (const float*)d_in[0];
    float* out = (float*)d_out;
    const int rows = in_sizes[0] / ROW_IN;  // 16384
    TNorm_71038759076547_kernel<<<rows, 256, 0, stream>>>(x, out);
}

// Round 2
// 253.197 us; speedup vs baseline: 1.0113x; 1.0113x over previous
//
#include <hip/hip_runtime.h>

// TNorm: out[b] = outer(g0, g1, g2, g3) flattened, g = x[b].reshape(4, 8).
// B=16384 rows, 32 inputs/row, 4096 outputs/row (fp32).
// Write-stream bound: 256 MiB out + 2 MiB in -> ~43 us floor at 6.3 TB/s.
//
// R1: 1 row/block (16384 blocks) gave 256 us (~1 TB/s) — per-block
// load->barrier->4-stores chain keeps the store pipe shallow. Now 8 rows
// per block: one cooperative stage + one barrier, then 32 dwordx4 stores
// per thread back-to-back (128 KB/block).

#define ROW_IN 32
#define ROW_OUT 4096
#define ROWS_PER_BLOCK 8

__global__ __launch_bounds__(256) void TNorm_71038759076547_kernel(
    const float* __restrict__ x, float* __restrict__ out) {
    __shared__ float g[ROWS_PER_BLOCK * ROW_IN];  // 1 KB

    const int t = threadIdx.x;
    const size_t row0 = (size_t)blockIdx.x * ROWS_PER_BLOCK;

    // Stage 8 rows (256 floats) with 64 float4 loads.
    if (t < ROWS_PER_BLOCK * (ROW_IN / 4)) {
        ((float4*)g)[t] = ((const float4*)(x + row0 * ROW_IN))[t];
    }
    __syncthreads();

    float4* outbase = (float4*)out + row0 * (ROW_OUT / 4);

#pragma unroll
    for (int r = 0; r < ROWS_PER_BLOCK; ++r) {
        const float* gr = g + r * ROW_IN;
        const float* g0 = gr;
        const float* g1 = gr + 8;
        const float* g2 = gr + 16;
        const float* g3 = gr + 24;

        const float4 g3lo = make_float4(g3[0], g3[1], g3[2], g3[3]);
        const float4 g3hi = make_float4(g3[4], g3[5], g3[6], g3[7]);

        float4* out4 = outbase + r * (ROW_OUT / 4);

#pragma unroll
        for (int i = 0; i < 4; ++i) {
            const int v = t + 256 * i;   // float4 index in row, 0..1023
            const int e = v << 2;        // element index
            const int j = (e >> 9) & 7;
            const int k = (e >> 6) & 7;
            const int l = (e >> 3) & 7;
            const float s = g0[j] * g1[k] * g2[l];
            const float4 gm = (e & 4) ? g3hi : g3lo;
            float4 r4;
            r4.x = s * gm.x;
            r4.y = s * gm.y;
            r4.z = s * gm.z;
            r4.w = s * gm.w;
            out4[v] = r4;
        }
    }
}

extern "C" void kernel_launch(void* const* d_in, const int* in_sizes, int n_in,
                              void* d_out, int out_size, void* d_ws, size_t ws_size,
                              hipStream_t stream) {
    const float* x = (const float*)d_in[0];
    float* out = (float*)d_out;
    const int rows = in_sizes[0] / ROW_IN;            // 16384
    const int blocks = rows / ROWS_PER_BLOCK;         // 2048
    TNorm_71038759076547_kernel<<<blocks, 256, 0, stream>>>(x, out);
}